// Round 1
// baseline (95.890 us; speedup 1.0000x reference)
//
#include <hip/hip_runtime.h>

#define BATCH   16384
#define NUM_NUM 32
#define NUM_CAT 32
#define CARD    128
#define OUT_F   32
#define XSTRIDE (NUM_NUM + NUM_CAT * CARD)   // 4128
#define OSTRIDE (NUM_NUM + NUM_CAT * OUT_F)  // 1056

#define TR   256   // rows per block
#define CK   32    // K chunk staged in LDS
#define XPAD (CK + 1)

// One block = one feature f x 256 batch rows.
// LDS: W[f] full (128x32 f32 = 16KB) + x chunk (256x33 f32 = 33KB) -> ~50KB -> 3 blocks/CU.
// Thread tile: 8 rows x 4 cols -> per c-iter 1x ds_read_b128 + 8x ds_read_b32 vs 32 FMA (FMA-bound).
__global__ __launch_bounds__(256, 1) void emb_gemm(const float* __restrict__ x,
                                                   const float* __restrict__ W,
                                                   const float* __restrict__ bias,
                                                   float* __restrict__ out) {
    __shared__ float w_s[CARD][OUT_F];  // [c][o], 16 KB
    __shared__ float x_s[TR][XPAD];     // [row][c], +1 pad -> bank (row+c)%32

    const int f    = blockIdx.y;
    const int row0 = blockIdx.x * TR;
    const int tid  = threadIdx.x;

    // Stage W[f]: 4096 floats = 1024 float4, 4 per thread, coalesced.
    {
        const float4* wg  = (const float4*)(W + (size_t)f * CARD * OUT_F);
        float4*       ws4 = (float4*)&w_s[0][0];
#pragma unroll
        for (int i = 0; i < 4; ++i) ws4[i * 256 + tid] = wg[i * 256 + tid];
    }

    const int og = tid & 7;   // 8 col-groups of 4 outputs
    const int rg = tid >> 3;  // 32 row-groups of 8 rows

    float acc[8][4];
#pragma unroll
    for (int j = 0; j < 8; ++j)
#pragma unroll
        for (int k = 0; k < 4; ++k) acc[j][k] = 0.0f;

    const float* xg_base = x + (size_t)row0 * XSTRIDE + NUM_NUM + f * CARD;

    for (int ck = 0; ck < CARD / CK; ++ck) {
        // Stage x chunk: 256 rows x 32 cols = 2048 float4, 8 per thread.
        // lanes 0..7 read 128B contiguous within one row -> coalesced segments.
        const float* xg = xg_base + ck * CK;
#pragma unroll
        for (int it = 0; it < 8; ++it) {
            int    idx = it * 256 + tid;
            int    r   = idx >> 3;
            int    c4  = (idx & 7) * 4;
            float4 v   = *(const float4*)(xg + (size_t)r * XSTRIDE + c4);
            x_s[r][c4 + 0] = v.x;
            x_s[r][c4 + 1] = v.y;
            x_s[r][c4 + 2] = v.z;
            x_s[r][c4 + 3] = v.w;
        }
        __syncthreads();

#pragma unroll 8
        for (int c = 0; c < CK; ++c) {
            float4 w4 = *(const float4*)&w_s[ck * CK + c][og * 4];
#pragma unroll
            for (int j = 0; j < 8; ++j) {
                float xv = x_s[rg * 8 + j][c];
                acc[j][0] += xv * w4.x;
                acc[j][1] += xv * w4.y;
                acc[j][2] += xv * w4.z;
                acc[j][3] += xv * w4.w;
            }
        }
        __syncthreads();
    }

    // Epilogue: add bias, store float4 (16B-aligned: 32 + f*32 + og*4 is x4 floats).
    float4 b4 = *(const float4*)(bias + f * OUT_F + og * 4);
#pragma unroll
    for (int j = 0; j < 8; ++j) {
        int    row = row0 + rg * 8 + j;
        float4 o4;
        o4.x = acc[j][0] + b4.x;
        o4.y = acc[j][1] + b4.y;
        o4.z = acc[j][2] + b4.z;
        o4.w = acc[j][3] + b4.w;
        *(float4*)(out + (size_t)row * OSTRIDE + NUM_NUM + f * OUT_F + og * 4) = o4;
    }
}

// Passthrough of the 32 numeric columns: 16384 rows x 8 float4.
__global__ __launch_bounds__(256) void num_copy(const float* __restrict__ x,
                                                float* __restrict__ out) {
    int    idx = blockIdx.x * 256 + threadIdx.x;  // 131072 total
    int    row = idx >> 3;
    int    c4  = (idx & 7) * 4;
    float4 v   = *(const float4*)(x + (size_t)row * XSTRIDE + c4);
    *(float4*)(out + (size_t)row * OSTRIDE + c4) = v;
}

extern "C" void kernel_launch(void* const* d_in, const int* in_sizes, int n_in,
                              void* d_out, int out_size, void* d_ws, size_t ws_size,
                              hipStream_t stream) {
    const float* x    = (const float*)d_in[0];
    const float* W    = (const float*)d_in[1];
    const float* bias = (const float*)d_in[2];
    float*       out  = (float*)d_out;

    dim3 grid(BATCH / TR, NUM_CAT);
    emb_gemm<<<grid, 256, 0, stream>>>(x, W, bias, out);
    num_copy<<<BATCH * 8 / 256, 256, 0, stream>>>(x, out);
}